// Round 8
// baseline (109.004 us; speedup 1.0000x reference)
//
#include <hip/hip_runtime.h>

#define TPB 256
#define REP 16   // DIAGNOSTIC ROUND: repeat per-pair compute 16x (CSE/DCE-proof)
                 // so k1 exceeds the ~40us poison fills and shows its rocprof
                 // counters, and so marginal-compute = (dur - fixed)/15.
                 // Round 9 flips this to 1.

// Scalar shared-denominator interval clip (round-7 math, scalarized, 1 pair
// per thread).  2*area(P∩Q) = sum over edges of both CCW quads of
// (t1-t0)*cross(A,B); one protected reciprocal per (i,k) serves both passes.
__global__ __launch_bounds__(TPB, 6) void obb_rep_kernel(
    const float4* __restrict__ pred, const float4* __restrict__ gt,
    const int* __restrict__ mask, float2* __restrict__ partial, int total)
{
    __shared__ float red_l[TPB / 64], red_m[TPB / 64];

    const int idx = blockIdx.x * TPB + threadIdx.x;
    float lacc = 0.f, macc = 0.f;

    if (idx < total) {
        const float4 p01 = pred[idx * 2], p23 = pred[idx * 2 + 1];
        const float4 g01 = gt[idx * 2],   g23 = gt[idx * 2 + 1];
        const float mval = (mask[idx] != 0) ? 1.f : 0.f;

        float loss = 0.f;
        #pragma unroll 1
        for (int r = 0; r < REP; ++r) {
            float px[4] = {p01.x, p01.z, p23.x, p23.z};
            float py[4] = {p01.y, p01.w, p23.y, p23.w};
            float gx[4] = {g01.x, g01.z, g23.x, g23.z};
            float gy[4] = {g01.y, g01.w, g23.y, g23.w};
            // CSE barrier: inputs look fresh every trip -> full recompute
            asm volatile("" : "+v"(px[0]), "+v"(px[1]), "+v"(px[2]), "+v"(px[3]));
            asm volatile("" : "+v"(py[0]), "+v"(py[1]), "+v"(py[2]), "+v"(py[3]));
            asm volatile("" : "+v"(gx[0]), "+v"(gx[1]), "+v"(gx[2]), "+v"(gx[3]));
            asm volatile("" : "+v"(gy[0]), "+v"(gy[1]), "+v"(gy[2]), "+v"(gy[3]));

            // shoelace (doubled signed areas)
            float ap2 = 0.f, ag2 = 0.f;
            #pragma unroll
            for (int i = 0; i < 4; ++i) {
                const int j = (i + 1) & 3;
                ap2 += px[i] * py[j] - py[i] * px[j];
                ag2 += gx[i] * gy[j] - gy[i] * gx[j];
            }

            // force CCW (swap v0<->v3, v1<->v2 where signed area < 0)
            {
                const bool cp = ap2 < 0.f, cg = ag2 < 0.f;
                #define SWP(u, v, c) { const float t_ = (c) ? (v) : (u); (v) = (c) ? (u) : (v); (u) = t_; }
                SWP(px[0], px[3], cp)  SWP(py[0], py[3], cp)
                SWP(px[1], px[2], cp)  SWP(py[1], py[2], cp)
                SWP(gx[0], gx[3], cg)  SWP(gy[0], gy[3], cg)
                SWP(gx[1], gx[2], cg)  SWP(gy[1], gy[2], cg)
                #undef SWP
            }

            // edge vectors + line constants: d(X) = e.x*X.y - e.y*X.x - c0
            float pex[4], pey[4], pc0[4], gex[4], gey[4], gc0[4];
            #pragma unroll
            for (int k = 0; k < 4; ++k) {
                const int k2 = (k + 1) & 3;
                pex[k] = px[k2] - px[k];  pey[k] = py[k2] - py[k];
                pc0[k] = pex[k] * py[k] - pey[k] * px[k];
                gex[k] = gx[k2] - gx[k];  gey[k] = gy[k2] - gy[k];
                gc0[k] = gex[k] * gy[k] - gey[k] * gx[k];
            }

            float loP[4], hiP[4], loQ[4], hiQ[4];
            #pragma unroll
            for (int i = 0; i < 4; ++i) {
                loP[i] = 0.f; hiP[i] = 1.f; loQ[i] = 0.f; hiQ[i] = 1.f;
            }

            #pragma unroll
            for (int i = 0; i < 4; ++i) {
                #pragma unroll
                for (int k = 0; k < 4; ++k) {
                    float C = gex[k] * pey[i] - gey[k] * pex[i]; // shared denom
                    C = (fabsf(C) < 1e-12f) ? 1e-12f : C;
                    const float R = __builtin_amdgcn_rcpf(C);
                    const float dPik = fmaf(gex[k], py[i], -fmaf(gey[k], px[i], gc0[k]));
                    const float dQki = fmaf(pex[i], gy[k], -fmaf(pey[i], gx[k], pc0[i]));
                    const float tP = -dPik * R;     // P-edge i vs Q-line k
                    const float tQ =  dQki * R;     // Q-edge k vs P-line i
                    const bool  f  = C > 0.f;
                    hiP[i] = f ? hiP[i] : fminf(hiP[i], tP);
                    loP[i] = f ? fmaxf(loP[i], tP) : loP[i];
                    hiQ[k] = f ? fminf(hiQ[k], tQ) : hiQ[k];
                    loQ[k] = f ? loQ[k] : fmaxf(loQ[k], tQ);
                }
            }

            float a2 = 0.f;
            #pragma unroll
            for (int e = 0; e < 4; ++e) {
                const int j = (e + 1) & 3;
                const float crP = px[e] * py[j] - py[e] * px[j];
                const float crQ = gx[e] * gy[j] - gy[e] * gx[j];
                a2 += fmaxf(hiP[e] - loP[e], 0.f) * crP
                    + fmaxf(hiQ[e] - loQ[e], 0.f) * crQ;
            }

            const float inter2 = fabsf(a2);
            const float uni2   = fabsf(ap2) + fabsf(ag2) - inter2;
            const float iou = (uni2 > 0.f) ? inter2 * __builtin_amdgcn_rcpf(uni2) : 0.f;
            loss = 1.f - iou;

            asm volatile("" :: "v"(loss));   // DCE sink for non-final trips
        }
        lacc = loss * mval;
        macc = mval;
    }

    // deterministic block reduction: wave shuffle then cross-wave LDS
    float l = lacc, m = macc;
    #pragma unroll
    for (int off = 32; off > 0; off >>= 1) {
        l += __shfl_down(l, off, 64);
        m += __shfl_down(m, off, 64);
    }
    const int wid  = threadIdx.x >> 6;
    const int lane = threadIdx.x & 63;
    if (lane == 0) { red_l[wid] = l; red_m[wid] = m; }
    __syncthreads();
    if (threadIdx.x == 0) {
        const float L = red_l[0] + red_l[1] + red_l[2] + red_l[3];
        const float M = red_m[0] + red_m[1] + red_m[2] + red_m[3];
        partial[blockIdx.x] = make_float2(L, M);
    }
}

// 1024 threads, strided partial loads -> double shuffle-reduce (fixed order).
__global__ __launch_bounds__(1024) void obb_finalize(
    const float2* __restrict__ partial, int nb, float* __restrict__ out)
{
    __shared__ double sl[16], sm[16];
    double l = 0.0, m = 0.0;
    for (int i = threadIdx.x; i < nb; i += 1024) {
        const float2 v = partial[i];
        l += (double)v.x;
        m += (double)v.y;
    }
    #pragma unroll
    for (int off = 32; off > 0; off >>= 1) {
        l += __shfl_down(l, off, 64);
        m += __shfl_down(m, off, 64);
    }
    const int wid  = threadIdx.x >> 6;
    const int lane = threadIdx.x & 63;
    if (lane == 0) { sl[wid] = l; sm[wid] = m; }
    __syncthreads();
    if (threadIdx.x == 0) {
        double L = 0.0, M = 0.0;
        #pragma unroll
        for (int w = 0; w < 16; ++w) { L += sl[w]; M += sm[w]; }
        const double mean = L / (M > 1.0 ? M : 1.0);
        out[0] = (M > 0.0) ? (float)mean : 0.f;
    }
}

extern "C" void kernel_launch(void* const* d_in, const int* in_sizes, int n_in,
                              void* d_out, int out_size, void* d_ws, size_t ws_size,
                              hipStream_t stream)
{
    const float4* pred = (const float4*)d_in[0];   // (B,N,8) f32
    const float4* gt   = (const float4*)d_in[1];   // (B,N,8) f32
    const int* mask    = (const int*)d_in[3];      // (B,N) bool->i32
    float* out = (float*)d_out;                    // scalar f32

    const int total  = in_sizes[0] / 8;            // B*N
    const int blocks = (total + TPB - 1) / TPB;    // 2048

    float2* partial = (float2*)d_ws;               // blocks * 8 B

    obb_rep_kernel<<<blocks, TPB, 0, stream>>>(pred, gt, mask, partial, total);
    obb_finalize<<<1, 1024, 0, stream>>>(partial, blocks, out);
}

// Round 9
// 14.146 us; speedup vs baseline: 7.7057x; 7.7057x over previous
//
#include <hip/hip_runtime.h>

#define TPB 256

__device__ __forceinline__ float rcpf_(float x) { return __builtin_amdgcn_rcpf(x); }

// 1 - IoU for one (pred,gt) ROTATED-RECTANGLE pair via boundary line-integral:
// 2*area(P∩Q) = sum over edges (A->B) of both CCW rects of (t1-t0)*cross(A,B),
// [t0,t1] = param interval of the edge inside the other rect.
//
// Rectangle structure (edge2 = -edge0, edge3 = -edge1) collapses the work:
//  - only 4 distinct denominators C[k][i] = cross(fQk,fPi), k,i in {0,1}
//    (all 16 are +-C) -> 4 protected rcps total;
//  - vertex line-distances follow from 4 base values by adding C's (affine);
//  - opposite lines: LQ{k+2}(X) = T - LQk(X), T = cross(fQ0,fQ1) (same for P/U);
//  - every interval sign & bound-type is compile-time; runtime only picks
//    via the 4 bools f = (C~>0).
// IoU is invariant to the reference's per-image (W*x,H*y) scaling, so
// image_size is unused.  Matches rounds 3-7's validated tie-break (P-pass
// keeps coincident boundary, Q-pass drops it).
__device__ __forceinline__ float pair_loss_rect(
    const float4 P01, const float4 P23, const float4 G01, const float4 G23)
{
    float p0x=P01.x, p0y=P01.y, p1x=P01.z, p1y=P01.w;
    float p2x=P23.x, p2y=P23.y, p3x=P23.z, p3y=P23.w;
    float q0x=G01.x, q0y=G01.y, q1x=G01.z, q1y=G01.w;
    float q2x=G23.x, q2y=G23.y, q3x=G23.z, q3y=G23.w;

    // per-edge vertex crosses (shoelace terms; reused as the area weights)
    float crP0 = p0x*p1y - p0y*p1x, crP1 = p1x*p2y - p1y*p2x;
    float crP2 = p2x*p3y - p2y*p3x, crP3 = p3x*p0y - p3y*p0x;
    float crQ0 = q0x*q1y - q0y*q1x, crQ1 = q1x*q2y - q1y*q2x;
    float crQ2 = q2x*q3y - q2y*q3x, crQ3 = q3x*q0y - q3y*q0x;
    const float ap2 = (crP0+crP1)+(crP2+crP3);
    const float ag2 = (crQ0+crQ1)+(crQ2+crQ3);

    // _make_quads output is always CCW (area=w*h>0); wave-skipped fixup keeps
    // arbitrary inputs correct at ~zero cost on this data.
    if (__builtin_expect(__any(ap2 < 0.f) || __any(ag2 < 0.f), 0)) {
        const bool cp = ap2 < 0.f, cg = ag2 < 0.f;
        #define SWP(a,b,c) { const float t_=(c)?(b):(a); (b)=(c)?(a):(b); (a)=t_; }
        SWP(p0x,p3x,cp) SWP(p0y,p3y,cp) SWP(p1x,p2x,cp) SWP(p1y,p2y,cp)
        SWP(q0x,q3x,cg) SWP(q0y,q3y,cg) SWP(q1x,q2x,cg) SWP(q1y,q2y,cg)
        #undef SWP
        crP0 = p0x*p1y - p0y*p1x;  crP1 = p1x*p2y - p1y*p2x;
        crP2 = p2x*p3y - p2y*p3x;  crP3 = p3x*p0y - p3y*p0x;
        crQ0 = q0x*q1y - q0y*q1x;  crQ1 = q1x*q2y - q1y*q2x;
        crQ2 = q2x*q3y - q2y*q3x;  crQ3 = q3x*q0y - q3y*q0x;
        // ap2/ag2 only used via fabsf below - stale sign is fine
    }

    const float fP0x = p1x-p0x, fP0y = p1y-p0y;   // P edges (rect: f2=-f0,f3=-f1)
    const float fP1x = p2x-p1x, fP1y = p2y-p1y;
    const float fQ0x = q1x-q0x, fQ0y = q1y-q0y;
    const float fQ1x = q2x-q1x, fQ1y = q2y-q1y;

    const float C00 = fQ0x*fP0y - fQ0y*fP0x;      // cross(fQk, fPi)
    const float C01 = fQ0x*fP1y - fQ0y*fP1x;
    const float C10 = fQ1x*fP0y - fQ1y*fP0x;
    const float C11 = fQ1x*fP1y - fQ1y*fP1x;
    const float T   = fQ0x*fQ1y - fQ0y*fQ1x;      // LQ0(q2) = LQ1(q3)
    const float U   = fP0x*fP1y - fP0y*fP1x;      // LP0(p2) = LP1(p3)

    // reference's protected-denominator semantics (|d|<1e-12 -> 1e-12)
    const float Ct00 = (fabsf(C00)<1e-12f)?1e-12f:C00;
    const float Ct01 = (fabsf(C01)<1e-12f)?1e-12f:C01;
    const float Ct10 = (fabsf(C10)<1e-12f)?1e-12f:C10;
    const float Ct11 = (fabsf(C11)<1e-12f)?1e-12f:C11;
    const bool f00 = Ct00>0.f, f01 = Ct01>0.f, f10 = Ct10>0.f, f11 = Ct11>0.f;
    const float R00 = rcpf_(Ct00), R01 = rcpf_(Ct01);
    const float R10 = rcpf_(Ct10), R11 = rcpf_(Ct11);

    // base line-distances via Delta = q0 - p0
    const float Dx = q0x-p0x,  Dy = q0y-p0y;
    const float e1x = Dx+fQ0x, e1y = Dy+fQ0y;     // q1 - p0
    const float e2x = Dx-fP0x, e2y = Dy-fP0y;     // q0 - p1
    const float a00 = -(fQ0x*Dy  - fQ0y*Dx);      // LQ0(p0)
    const float a10 = -(fQ1x*e1y - fQ1y*e1x);     // LQ1(p0)
    const float b00 =  (fP0x*Dy  - fP0y*Dx);      // LP0(q0)
    const float b10 =  (fP1x*e2y - fP1y*e2x);     // LP1(q0)

    // affine vertex chains (each vertex step adds a precomputed cross)
    const float a01 = a00+C00, a02 = a01+C01, a03 = a00+C01;  // LQ0(p1,p2,p3)
    const float a11 = a10+C10, a12 = a11+C11, a13 = a10+C11;  // LQ1(p1,p2,p3)
    const float b01 = b00-C00, b02 = b01-C10, b03 = b00-C10;  // LP0(q1,q2,q3)
    const float b11 = b10-C01, b12 = b11-C11, b13 = b10-C11;  // LP1(q1,q2,q3)

    // R-scaled distances; m[k][i] = a[k][i]*R[k][i&1], n[i][k] = b[i][k]*R[k&1][i]
    const float m00=a00*R00, m01=a01*R01, m02=a02*R00, m03=a03*R01;
    const float m10=a10*R10, m11=a11*R11, m12=a12*R10, m13=a13*R11;
    const float n00=b00*R00, n01=b01*R10, n02=b02*R00, n03=b03*R10;
    const float n10=b10*R01, n11=b11*R11, n12=b12*R01, n13=b13*R11;
    const float TR00=T*R00, TR01=T*R01, TR10=T*R10, TR11=T*R11;
    const float UR00=U*R00, UR01=U*R01, UR10=U*R10, UR11=U*R11;

    // bound selects: non-binding uppers fold to 1.0, lowers to 0.0 (inline consts)
    #define UV(t,u) ((u)?(t):1.f)
    #define LV(t,u) ((u)?0.f:(t))
    float hi, lo, a2;
    // P-edge 0
    hi = fminf(fminf(UV(-m00,!f00),UV(-m10,!f10)), fminf(UV(TR00-m00,f00),UV(TR10-m10,f10)));
    lo = fmaxf(fmaxf(LV(-m00,!f00),LV(-m10,!f10)), fmaxf(LV(TR00-m00,f00),LV(TR10-m10,f10)));
    a2 = fmaxf(hi-lo,0.f)*crP0;
    // P-edge 1
    hi = fminf(fminf(UV(-m01,!f01),UV(-m11,!f11)), fminf(UV(TR01-m01,f01),UV(TR11-m11,f11)));
    lo = fmaxf(fmaxf(LV(-m01,!f01),LV(-m11,!f11)), fmaxf(LV(TR01-m01,f01),LV(TR11-m11,f11)));
    a2 = fmaf(fmaxf(hi-lo,0.f),crP1,a2);
    // P-edge 2
    hi = fminf(fminf(UV(m02,f00),UV(m12,f10)), fminf(UV(m02-TR00,!f00),UV(m12-TR10,!f10)));
    lo = fmaxf(fmaxf(LV(m02,f00),LV(m12,f10)), fmaxf(LV(m02-TR00,!f00),LV(m12-TR10,!f10)));
    a2 = fmaf(fmaxf(hi-lo,0.f),crP2,a2);
    // P-edge 3
    hi = fminf(fminf(UV(m03,f01),UV(m13,f11)), fminf(UV(m03-TR01,!f01),UV(m13-TR11,!f11)));
    lo = fmaxf(fmaxf(LV(m03,f01),LV(m13,f11)), fmaxf(LV(m03-TR01,!f01),LV(m13-TR11,!f11)));
    a2 = fmaf(fmaxf(hi-lo,0.f),crP3,a2);
    // Q-edge 0
    hi = fminf(fminf(UV(n00,f00),UV(n10,f01)), fminf(UV(n00-UR00,!f00),UV(n10-UR01,!f01)));
    lo = fmaxf(fmaxf(LV(n00,f00),LV(n10,f01)), fmaxf(LV(n00-UR00,!f00),LV(n10-UR01,!f01)));
    a2 = fmaf(fmaxf(hi-lo,0.f),crQ0,a2);
    // Q-edge 1
    hi = fminf(fminf(UV(n01,f10),UV(n11,f11)), fminf(UV(n01-UR10,!f10),UV(n11-UR11,!f11)));
    lo = fmaxf(fmaxf(LV(n01,f10),LV(n11,f11)), fmaxf(LV(n01-UR10,!f10),LV(n11-UR11,!f11)));
    a2 = fmaf(fmaxf(hi-lo,0.f),crQ1,a2);
    // Q-edge 2
    hi = fminf(fminf(UV(-n02,!f00),UV(-n12,!f01)), fminf(UV(UR00-n02,f00),UV(UR01-n12,f01)));
    lo = fmaxf(fmaxf(LV(-n02,!f00),LV(-n12,!f01)), fmaxf(LV(UR00-n02,f00),LV(UR01-n12,f01)));
    a2 = fmaf(fmaxf(hi-lo,0.f),crQ2,a2);
    // Q-edge 3
    hi = fminf(fminf(UV(-n03,!f10),UV(-n13,!f11)), fminf(UV(UR10-n03,f10),UV(UR11-n13,f11)));
    lo = fmaxf(fmaxf(LV(-n03,!f10),LV(-n13,!f11)), fmaxf(LV(UR10-n03,f10),LV(UR11-n13,f11)));
    a2 = fmaf(fmaxf(hi-lo,0.f),crQ3,a2);
    #undef UV
    #undef LV

    const float inter2 = fabsf(a2);
    const float uni2   = fabsf(ap2) + fabsf(ag2) - inter2;
    return 1.f - ((uni2 > 0.f) ? inter2 * rcpf_(uni2) : 0.f);
}

// Two ADJACENT pairs per thread: 64 B contiguous per lane per tensor.
__global__ __launch_bounds__(TPB, 4) void obb_pair_kernel(
    const float4* __restrict__ pred, const float4* __restrict__ gt,
    const int* __restrict__ mask, float2* __restrict__ partial,
    int npair2, int total)
{
    __shared__ float red_l[TPB / 64], red_m[TPB / 64];

    const int tp = blockIdx.x * TPB + threadIdx.x;
    float lacc = 0.f, macc = 0.f;

    if (tp < npair2) {
        const int iA = 2 * tp;
        const bool vB = (iA + 1) < total;

        const float4 pA0 = pred[2*iA],   pA1 = pred[2*iA+1];
        const float4 gA0 = gt[2*iA],     gA1 = gt[2*iA+1];
        const int    mA  = mask[iA];
        float4 pB0, pB1, gB0, gB1; int mB = 0;
        if (vB) {
            pB0 = pred[2*iA+2];  pB1 = pred[2*iA+3];
            gB0 = gt[2*iA+2];    gB1 = gt[2*iA+3];
            mB  = mask[iA+1];
        }

        const float lA = pair_loss_rect(pA0, pA1, gA0, gA1);
        lacc = (mA != 0) ? lA : 0.f;
        macc = (mA != 0) ? 1.f : 0.f;
        if (vB) {
            const float lB = pair_loss_rect(pB0, pB1, gB0, gB1);
            lacc += (mB != 0) ? lB : 0.f;
            macc += (mB != 0) ? 1.f : 0.f;
        }
    }

    // deterministic block reduction: wave shuffle then cross-wave LDS
    float l = lacc, m = macc;
    #pragma unroll
    for (int off = 32; off > 0; off >>= 1) {
        l += __shfl_down(l, off, 64);
        m += __shfl_down(m, off, 64);
    }
    const int wid  = threadIdx.x >> 6;
    const int lane = threadIdx.x & 63;
    if (lane == 0) { red_l[wid] = l; red_m[wid] = m; }
    __syncthreads();
    if (threadIdx.x == 0) {
        const float L = red_l[0] + red_l[1] + red_l[2] + red_l[3];
        const float M = red_m[0] + red_m[1] + red_m[2] + red_m[3];
        partial[blockIdx.x] = make_float2(L, M);
    }
}

// 1024 threads, 1 partial per thread -> double shuffle-reduce (fixed order).
__global__ __launch_bounds__(1024) void obb_finalize(
    const float2* __restrict__ partial, int nb, float* __restrict__ out)
{
    __shared__ double sl[16], sm[16];
    double l = 0.0, m = 0.0;
    for (int i = threadIdx.x; i < nb; i += 1024) {
        const float2 v = partial[i];
        l += (double)v.x;
        m += (double)v.y;
    }
    #pragma unroll
    for (int off = 32; off > 0; off >>= 1) {
        l += __shfl_down(l, off, 64);
        m += __shfl_down(m, off, 64);
    }
    const int wid  = threadIdx.x >> 6;
    const int lane = threadIdx.x & 63;
    if (lane == 0) { sl[wid] = l; sm[wid] = m; }
    __syncthreads();
    if (threadIdx.x == 0) {
        double L = 0.0, M = 0.0;
        #pragma unroll
        for (int w = 0; w < 16; ++w) { L += sl[w]; M += sm[w]; }
        const double mean = L / (M > 1.0 ? M : 1.0);
        out[0] = (M > 0.0) ? (float)mean : 0.f;
    }
}

extern "C" void kernel_launch(void* const* d_in, const int* in_sizes, int n_in,
                              void* d_out, int out_size, void* d_ws, size_t ws_size,
                              hipStream_t stream)
{
    const float4* pred = (const float4*)d_in[0];   // (B,N,8) f32
    const float4* gt   = (const float4*)d_in[1];   // (B,N,8) f32
    const int* mask    = (const int*)d_in[3];      // (B,N) bool->i32
    float* out = (float*)d_out;                    // scalar f32

    const int total  = in_sizes[0] / 8;            // B*N
    const int npair2 = (total + 1) / 2;
    const int blocks = (npair2 + TPB - 1) / TPB;   // 1024

    float2* partial = (float2*)d_ws;               // blocks * 8 B

    obb_pair_kernel<<<blocks, TPB, 0, stream>>>(pred, gt, mask, partial,
                                                npair2, total);
    obb_finalize<<<1, 1024, 0, stream>>>(partial, blocks, out);
}